// Round 11
// baseline (214.454 us; speedup 1.0000x reference)
//
#include <hip/hip_runtime.h>

#define N_NODES 100000
#define N_EDGES 1600000
#define BN_EPS 1e-5f
#define SB 25          // super-buckets of 4096 nodes
#define SCAP 69632     // super capacity (mean 64000 + 22 sigma), 17*4096
#define NBB 800        // SB*32 buckets of 128 nodes
#define CAP 2688       // bucket capacity (mean 2048 + 14 sigma)

typedef short short8 __attribute__((ext_vector_type(8)));
typedef float floatx4 __attribute__((ext_vector_type(4)));

__device__ __forceinline__ unsigned short f2bf(float f) {
    unsigned int u = __float_as_uint(f);
    unsigned int r = (u + 0x7fffu + ((u >> 16) & 1u)) >> 16;  // RNE
    return (unsigned short)r;
}
__device__ __forceinline__ float bflo(unsigned int v) { return __uint_as_float(v << 16); }
__device__ __forceinline__ float bfhi(unsigned int v) { return __uint_as_float(v & 0xffff0000u); }

// ---------------- pass A: edges -> 25 super-buckets (coalesced runs ~164) ----------------
// code = src | (dst_local12 << 17)
__global__ __launch_bounds__(512) void k_binA(const int* __restrict__ ei,
                                              int* __restrict__ scnt,
                                              unsigned int* __restrict__ b1, int E) {
    __shared__ int hist[32], base[32], gbase[32];
    __shared__ unsigned int stage[4096];
    __shared__ unsigned char stb[4096];
    int tid = threadIdx.x;
    int e0 = blockIdx.x * 4096;
    int cn = min(4096, E - e0);
    if (tid < 32) hist[tid] = 0;
    __syncthreads();

    unsigned int mycode[8];
    short myslot[8];
    signed char myb[8];
    #pragma unroll
    for (int j = 0; j < 8; j++) {
        int idx = j * 512 + tid;
        if (idx < cn) {
            int src = ei[e0 + idx];
            int dst = ei[E + e0 + idx];
            int s = dst >> 12;
            mycode[j] = (unsigned int)src | ((unsigned int)(dst & 4095) << 17);
            myb[j] = (signed char)s;
            myslot[j] = (short)atomicAdd(&hist[s], 1);
        } else myb[j] = -1;
    }
    __syncthreads();
    if (tid == 0) {
        int run = 0;
        for (int s = 0; s < SB; s++) { base[s] = run; run += hist[s]; }
    }
    __syncthreads();
    #pragma unroll
    for (int j = 0; j < 8; j++) {
        if (myb[j] >= 0) {
            int p = base[myb[j]] + myslot[j];
            stage[p] = mycode[j];
            stb[p] = (unsigned char)myb[j];
        }
    }
    if (tid < SB && hist[tid]) gbase[tid] = tid * SCAP + atomicAdd(&scnt[tid], hist[tid]);
    __syncthreads();
    for (int i = tid; i < cn; i += 512) {
        int s = stb[i];
        b1[gbase[s] + (i - base[s])] = stage[i];
    }
}

// ---------------- pass B: super-bucket -> 32 buckets of 128 nodes (runs = 128) ----------------
// final code = src | (dst_local7 << 17)
__global__ __launch_bounds__(512) void k_binB(const unsigned int* __restrict__ b1,
                                              const int* __restrict__ scnt,
                                              int* __restrict__ bcnt,
                                              unsigned int* __restrict__ b2) {
    __shared__ int hist[32], base[32], gbase[32];
    __shared__ unsigned int stage[4096];
    __shared__ unsigned char stb[4096];
    int tid = threadIdx.x;
    int s = blockIdx.x / 17;
    int c = blockIdx.x % 17;
    int cnt = scnt[s];
    int e0 = s * SCAP + c * 4096;
    int cn = min(4096, cnt - c * 4096);
    if (tid < 32) hist[tid] = 0;
    __syncthreads();

    unsigned int mycode[8];
    short myslot[8];
    signed char myb[8];
    #pragma unroll
    for (int j = 0; j < 8; j++) {
        int idx = j * 512 + tid;
        if (idx < cn) {
            unsigned int code = b1[e0 + idx];
            int sub = (code >> 24) & 31;          // dst_local12 >> 7
            mycode[j] = code & 0x00FFFFFFu;       // src | dst_local7<<17
            myb[j] = (signed char)sub;
            myslot[j] = (short)atomicAdd(&hist[sub], 1);
        } else myb[j] = -1;
    }
    __syncthreads();
    if (tid == 0) {
        int run = 0;
        for (int k = 0; k < 32; k++) { base[k] = run; run += hist[k]; }
    }
    __syncthreads();
    #pragma unroll
    for (int j = 0; j < 8; j++) {
        if (myb[j] >= 0) {
            int p = base[myb[j]] + myslot[j];
            stage[p] = mycode[j];
            stb[p] = (unsigned char)myb[j];
        }
    }
    if (tid < 32 && hist[tid]) {
        int gb = s * 32 + tid;
        gbase[tid] = gb * CAP + atomicAdd(&bcnt[gb], hist[tid]);
    }
    __syncthreads();
    for (int i = tid; i < cn; i += 512) {
        int sub = stb[i];
        b2[gbase[sub] + (i - base[sub])] = stage[i];
    }
}

// ---------------- per-bucket: sort codes in place (b2 -> node-grouped src), deg/offs/dinv ----------------
__global__ __launch_bounds__(256) void k_sortd(unsigned int* __restrict__ b2,
        const int* __restrict__ bcnt, int* __restrict__ offs, int* __restrict__ deg,
        float* __restrict__ dinv, int n) {
    __shared__ unsigned int stage[CAP];
    __shared__ int hist[128], hsc[128];
    int b = blockIdx.x, t = threadIdx.x;
    int nb0 = b * 128;
    int e0 = b * CAP;
    int cnt = bcnt[b];
    if (t < 128) hist[t] = 0;
    __syncthreads();
    for (int i = t; i < cnt; i += 256) {
        unsigned int code = b2[e0 + i];
        stage[i] = code;
        atomicAdd(&hist[code >> 17], 1);
    }
    __syncthreads();
    int v = (t < 128) ? hist[t] : 0;
    if (t < 128) hsc[t] = v;
    __syncthreads();
    for (int o = 1; o < 128; o <<= 1) {
        int x = (t < 128 && t >= o) ? hsc[t - o] : 0;
        __syncthreads();
        if (t < 128) hsc[t] += x;
        __syncthreads();
    }
    int nr = min(128, n - nb0);
    if (t < nr) {
        int start = hsc[t] - v;
        offs[nb0 + t] = e0 + start;
        deg[nb0 + t] = v;
        dinv[nb0 + t] = rsqrtf((float)(v + 1));
        hist[t] = start;          // reuse as scatter cursor
    }
    __syncthreads();
    for (int i = t; i < cnt; i += 256) {
        unsigned int code = stage[i];
        int pos = atomicAdd(&hist[code >> 17], 1);
        b2[e0 + pos] = code & 0x1FFFF;   // src only
    }
}

// ---------------- W f32 -> bf16 ----------------
__global__ void k_wcvt(const float* __restrict__ Wf, unsigned short* __restrict__ Wb) {
    int i = blockIdx.x * 256 + threadIdx.x;
    if (i < 128 * 128) Wb[i] = f2bf(Wf[i]);
}

// ---------------- GEMM g = dinv * (x @ W^T) via bf16 MFMA, g stored as bf16 ----------------
__global__ __launch_bounds__(256) void k_gemm(const float* __restrict__ x,
                                              const unsigned short* __restrict__ Wb,
                                              const float* __restrict__ dinv,
                                              unsigned short* __restrict__ gb, int n) {
    int w = threadIdx.x >> 6;
    int l = threadIdx.x & 63;
    int rowbase = blockIdx.x * 128 + w * 32;
    int r16 = l & 15;
    int kg = l >> 4;

    short8 a[2][4];
    float dv[2][4];
    #pragma unroll
    for (int m = 0; m < 2; m++) {
        int row = rowbase + m * 16 + r16;
        int rca = min(row, n - 1);
        const float* base = x + rca * 128;
        #pragma unroll
        for (int q = 0; q < 4; q++) {
            const float4* xp = (const float4*)(base + q * 32 + kg * 8);
            float4 lo = xp[0], hi = xp[1];
            short8 af;
            af[0] = (short)f2bf(lo.x); af[1] = (short)f2bf(lo.y);
            af[2] = (short)f2bf(lo.z); af[3] = (short)f2bf(lo.w);
            af[4] = (short)f2bf(hi.x); af[5] = (short)f2bf(hi.y);
            af[6] = (short)f2bf(hi.z); af[7] = (short)f2bf(hi.w);
            a[m][q] = af;
        }
        #pragma unroll
        for (int r = 0; r < 4; r++)
            dv[m][r] = dinv[min(rowbase + m * 16 + kg * 4 + r, n - 1)];
    }
    for (int t = 0; t < 8; t++) {
        int col = t * 16 + r16;
        short8 b[4];
        #pragma unroll
        for (int q = 0; q < 4; q++)
            b[q] = *(const short8*)(Wb + col * 128 + q * 32 + kg * 8);

        floatx4 acc[2] = {};
        #pragma unroll
        for (int m = 0; m < 2; m++)
            #pragma unroll
            for (int q = 0; q < 4; q++)
                acc[m] = __builtin_amdgcn_mfma_f32_16x16x32_bf16(a[m][q], b[q], acc[m], 0, 0, 0);

        #pragma unroll
        for (int m = 0; m < 2; m++) {
            #pragma unroll
            for (int r = 0; r < 4; r++) {
                int row = rowbase + m * 16 + kg * 4 + r;
                if (row < n) gb[row * 128 + col] = f2bf(acc[m][r] * dv[m][r]);
            }
        }
    }
}

// ---------------- aggregation: column-split, wave per (node, col-half), no LDS ----------------
// out_i = dinv_i * (g_i + sum_e g_src); half-wave processes one edge's 128B half-row
__global__ __launch_bounds__(256) void k_agg(const unsigned int* __restrict__ hp,
        const float* __restrict__ dinv, const int* __restrict__ offs,
        const int* __restrict__ deg, const unsigned int* __restrict__ csr,
        float* __restrict__ out, int n) {
    int t = threadIdx.x;
    int w = t >> 6, l = t & 63;
    int bid = blockIdx.x;
    int nblk = bid >> 1;
    int ch = bid & 1;               // column half
    int half = l >> 5;              // which edge of the pair
    int cu = ch * 32 + (l & 31);    // uint column (2 bf16 cols)
    int i = nblk * 4 + w;
    if (i >= n) return;
    float di = dinv[i];
    int s0 = offs[i];
    int dg = deg[i];
    float ax = 0.f, ay = 0.f;
    for (int base = 0; base < dg; base += 64) {
        int rem = min(dg - base, 64);
        unsigned int mysrc = (l < rem) ? csr[s0 + base + l] : 0;
        int e = 0;
        for (; e + 15 < rem; e += 16) {     // 8 loads/lane
            unsigned int hv[8];
            #pragma unroll
            for (int j = 0; j < 8; j++) {
                int s = __shfl(mysrc, e + 2 * j + half);
                hv[j] = hp[s * 64 + cu];
            }
            #pragma unroll
            for (int j = 0; j < 8; j++) {
                ax += bflo(hv[j]);
                ay += bfhi(hv[j]);
            }
        }
        for (; e + 1 < rem; e += 2) {
            int s = __shfl(mysrc, e + half);
            unsigned int hv = hp[s * 64 + cu];
            ax += bflo(hv);
            ay += bfhi(hv);
        }
        if (e < rem) {                       // odd leftover: half 0 only
            int s = __shfl(mysrc, e);
            if (half == 0) {
                unsigned int hv = hp[s * 64 + cu];
                ax += bflo(hv);
                ay += bfhi(hv);
            }
        }
    }
    ax += __shfl_xor(ax, 32);
    ay += __shfl_xor(ay, 32);
    if (half == 0) {
        unsigned int sv = hp[i * 64 + cu];   // self term g_i
        float v0 = di * (ax + bflo(sv));
        float v1 = di * (ay + bfhi(sv));
        ((float2*)out)[i * 64 + cu] = make_float2(v0, v1);
    }
}

// ---------------- BN stats from f32 out ----------------
__global__ void k_stats(const float* __restrict__ out, float* __restrict__ sums,
                        float* __restrict__ sumsq, int n) {
    int tid = threadIdx.x;
    int c2 = tid & 63;
    int rh = tid >> 6;  // 0..3
    float s0 = 0, s1 = 0, q0 = 0, q1 = 0;
    for (int r = blockIdx.x * 4 + rh; r < n; r += gridDim.x * 4) {
        float2 v = ((const float2*)out)[r * 64 + c2];
        s0 += v.x; q0 += v.x * v.x;
        s1 += v.y; q1 += v.y * v.y;
    }
    __shared__ float ls[4][128], lq[4][128];
    ls[rh][2 * c2] = s0; ls[rh][2 * c2 + 1] = s1;
    lq[rh][2 * c2] = q0; lq[rh][2 * c2 + 1] = q1;
    __syncthreads();
    if (tid < 128) {
        float s = 0, q = 0;
        #pragma unroll
        for (int j = 0; j < 4; j++) { s += ls[j][tid]; q += lq[j][tid]; }
        atomicAdd(&sums[tid], s);
        atomicAdd(&sumsq[tid], q);
    }
}

// ---------------- BN normalize + ReLU (in place on f32 out) ----------------
__global__ void k_bn(float* __restrict__ out, const float* __restrict__ sums,
                     const float* __restrict__ sumsq, const float* __restrict__ gamma,
                     const float* __restrict__ beta, int n) {
    int idx = blockIdx.x * 256 + threadIdx.x;
    int total = n * 32;
    if (idx >= total) return;
    int c0 = (idx & 31) * 4;
    float invN = 1.0f / (float)n;
    float4 v = ((const float4*)out)[idx];
    float r[4] = {v.x, v.y, v.z, v.w};
    #pragma unroll
    for (int j = 0; j < 4; j++) {
        int c = c0 + j;
        float mean = sums[c] * invN;
        float var = sumsq[c] * invN - mean * mean;
        float scale = rsqrtf(var + BN_EPS) * gamma[c];
        float o = (r[j] - mean) * scale + beta[c];
        r[j] = fmaxf(o, 0.0f);
    }
    ((float4*)out)[idx] = make_float4(r[0], r[1], r[2], r[3]);
}

extern "C" void kernel_launch(void* const* d_in, const int* in_sizes, int n_in,
                              void* d_out, int out_size, void* d_ws, size_t ws_size,
                              hipStream_t stream) {
    const float* x     = (const float*)d_in[0];
    const int*   ei    = (const int*)d_in[1];     // [2][E]
    const float* W     = (const float*)d_in[2];
    // d_in[3] = b : cancels exactly under training-mode BatchNorm -> unused
    const float* gamma = (const float*)d_in[4];
    const float* beta  = (const float*)d_in[5];
    float* out = (float*)d_out;

    const int n = N_NODES, E = N_EDGES;

    // workspace layout (~43 MB)
    unsigned short* gbuf = (unsigned short*)d_ws;          // 12.8M bf16 (25.6 MB)
    float* dinv   = (float*)(gbuf + 12800000);             // 100k f32
    int*   offs   = (int*)(dinv + 100000);                 // 100k
    int*   deg    = offs + 100000;                         // 100k
    float* sums   = (float*)(deg + 100000);                // 128  (zero region start)
    float* sumsq  = sums + 128;                            // 128
    int*   bcnt   = (int*)(sumsq + 128);                   // NBB
    int*   scnt   = bcnt + NBB;                            // SB   (zero region end)
    unsigned short* Wb = (unsigned short*)(scnt + SB);     // 16384 bf16
    unsigned int* b1 = (unsigned int*)(Wb + 16384);        // SB*SCAP u32 (7.0 MB)
    unsigned int* b2 = b1 + SB * SCAP;                     // NBB*CAP u32 (8.6 MB), becomes CSR

    hipMemsetAsync(sums, 0, (256 + NBB + SB) * sizeof(int), stream);

    k_binA<<<(E + 4095) / 4096, 512, 0, stream>>>(ei, scnt, b1, E);
    k_binB<<<SB * 17, 512, 0, stream>>>(b1, scnt, bcnt, b2);
    k_sortd<<<NBB, 256, 0, stream>>>(b2, bcnt, offs, deg, dinv, n);

    k_wcvt<<<64, 256, 0, stream>>>(W, Wb);
    k_gemm<<<(n + 127) / 128, 256, 0, stream>>>(x, Wb, dinv, gbuf, n);

    k_agg<<<((n + 3) / 4) * 2, 256, 0, stream>>>((const unsigned int*)gbuf, dinv, offs, deg,
                                                 (const unsigned int*)b2, out, n);

    k_stats<<<512, 256, 0, stream>>>(out, sums, sumsq, n);
    k_bn<<<(n * 32 + 255) / 256, 256, 0, stream>>>(out, sums, sumsq, gamma, beta, n);
}

// Round 12
// 167.624 us; speedup vs baseline: 1.2794x; 1.2794x over previous
//
#include <hip/hip_runtime.h>

#define N_NODES 100000
#define N_EDGES 1600000
#define BN_EPS 1e-5f
#define SB 25          // super-buckets of 4096 nodes
#define SCAP 69632     // super capacity (mean 64000 + 22 sigma), 17*4096
#define NBB 800        // SB*32 buckets of 128 nodes
#define CAP 2688       // bucket capacity (mean 2048 + 14 sigma)

typedef short short8 __attribute__((ext_vector_type(8)));
typedef float floatx4 __attribute__((ext_vector_type(4)));

__device__ __forceinline__ unsigned short f2bf(float f) {
    unsigned int u = __float_as_uint(f);
    unsigned int r = (u + 0x7fffu + ((u >> 16) & 1u)) >> 16;  // RNE
    return (unsigned short)r;
}
__device__ __forceinline__ float bflo(unsigned int v) { return __uint_as_float(v << 16); }
__device__ __forceinline__ float bfhi(unsigned int v) { return __uint_as_float(v & 0xffff0000u); }

// ---------------- pass A: edges -> 25 super-buckets (coalesced runs ~164) ----------------
// code = src | (dst_local12 << 17)
__global__ __launch_bounds__(512) void k_binA(const int* __restrict__ ei,
                                              int* __restrict__ scnt,
                                              unsigned int* __restrict__ b1, int E) {
    __shared__ int hist[32], base[32], gbase[32];
    __shared__ unsigned int stage[4096];
    __shared__ unsigned char stb[4096];
    int tid = threadIdx.x;
    int e0 = blockIdx.x * 4096;
    int cn = min(4096, E - e0);
    if (tid < 32) hist[tid] = 0;
    __syncthreads();

    unsigned int mycode[8];
    short myslot[8];
    signed char myb[8];
    #pragma unroll
    for (int j = 0; j < 8; j++) {
        int idx = j * 512 + tid;
        if (idx < cn) {
            int src = ei[e0 + idx];
            int dst = ei[E + e0 + idx];
            int s = dst >> 12;
            mycode[j] = (unsigned int)src | ((unsigned int)(dst & 4095) << 17);
            myb[j] = (signed char)s;
            myslot[j] = (short)atomicAdd(&hist[s], 1);
        } else myb[j] = -1;
    }
    __syncthreads();
    if (tid == 0) {
        int run = 0;
        for (int s = 0; s < SB; s++) { base[s] = run; run += hist[s]; }
    }
    __syncthreads();
    #pragma unroll
    for (int j = 0; j < 8; j++) {
        if (myb[j] >= 0) {
            int p = base[myb[j]] + myslot[j];
            stage[p] = mycode[j];
            stb[p] = (unsigned char)myb[j];
        }
    }
    if (tid < SB && hist[tid]) gbase[tid] = tid * SCAP + atomicAdd(&scnt[tid], hist[tid]);
    __syncthreads();
    for (int i = tid; i < cn; i += 512) {
        int s = stb[i];
        b1[gbase[s] + (i - base[s])] = stage[i];
    }
}

// ---------------- pass B: super-bucket -> 32 buckets of 128 nodes (runs = 128) ----------------
// final code = src | (dst_local7 << 17)
__global__ __launch_bounds__(512) void k_binB(const unsigned int* __restrict__ b1,
                                              const int* __restrict__ scnt,
                                              int* __restrict__ bcnt,
                                              unsigned int* __restrict__ b2) {
    __shared__ int hist[32], base[32], gbase[32];
    __shared__ unsigned int stage[4096];
    __shared__ unsigned char stb[4096];
    int tid = threadIdx.x;
    int s = blockIdx.x / 17;
    int c = blockIdx.x % 17;
    int cnt = scnt[s];
    int e0 = s * SCAP + c * 4096;
    int cn = min(4096, cnt - c * 4096);
    if (tid < 32) hist[tid] = 0;
    __syncthreads();

    unsigned int mycode[8];
    short myslot[8];
    signed char myb[8];
    #pragma unroll
    for (int j = 0; j < 8; j++) {
        int idx = j * 512 + tid;
        if (idx < cn) {
            unsigned int code = b1[e0 + idx];
            int sub = (code >> 24) & 31;          // dst_local12 >> 7
            mycode[j] = code & 0x00FFFFFFu;       // src | dst_local7<<17
            myb[j] = (signed char)sub;
            myslot[j] = (short)atomicAdd(&hist[sub], 1);
        } else myb[j] = -1;
    }
    __syncthreads();
    if (tid == 0) {
        int run = 0;
        for (int k = 0; k < 32; k++) { base[k] = run; run += hist[k]; }
    }
    __syncthreads();
    #pragma unroll
    for (int j = 0; j < 8; j++) {
        if (myb[j] >= 0) {
            int p = base[myb[j]] + myslot[j];
            stage[p] = mycode[j];
            stb[p] = (unsigned char)myb[j];
        }
    }
    if (tid < 32 && hist[tid]) {
        int gb = s * 32 + tid;
        gbase[tid] = gb * CAP + atomicAdd(&bcnt[gb], hist[tid]);
    }
    __syncthreads();
    for (int i = tid; i < cn; i += 512) {
        int sub = stb[i];
        b2[gbase[sub] + (i - base[sub])] = stage[i];
    }
}

// ---------------- per-bucket: sort codes in place (b2 -> node-grouped src), deg/offs/dinv ----------------
__global__ __launch_bounds__(256) void k_sortd(unsigned int* __restrict__ b2,
        const int* __restrict__ bcnt, int* __restrict__ offs, int* __restrict__ deg,
        float* __restrict__ dinv, int n) {
    __shared__ unsigned int stage[CAP];
    __shared__ int hist[128], hsc[128];
    int b = blockIdx.x, t = threadIdx.x;
    int nb0 = b * 128;
    int e0 = b * CAP;
    int cnt = bcnt[b];
    if (t < 128) hist[t] = 0;
    __syncthreads();
    for (int i = t; i < cnt; i += 256) {
        unsigned int code = b2[e0 + i];
        stage[i] = code;
        atomicAdd(&hist[code >> 17], 1);
    }
    __syncthreads();
    int v = (t < 128) ? hist[t] : 0;
    if (t < 128) hsc[t] = v;
    __syncthreads();
    for (int o = 1; o < 128; o <<= 1) {
        int x = (t < 128 && t >= o) ? hsc[t - o] : 0;
        __syncthreads();
        if (t < 128) hsc[t] += x;
        __syncthreads();
    }
    int nr = min(128, n - nb0);
    if (t < nr) {
        int start = hsc[t] - v;
        offs[nb0 + t] = start;            // local offset within bucket
        deg[nb0 + t] = v;
        dinv[nb0 + t] = rsqrtf((float)(v + 1));
        hist[t] = start;                  // reuse as scatter cursor
    }
    __syncthreads();
    for (int i = t; i < cnt; i += 256) {
        unsigned int code = stage[i];
        int pos = atomicAdd(&hist[code >> 17], 1);
        b2[e0 + pos] = code & 0x1FFFF;    // src only
    }
}

// ---------------- W f32 -> bf16 ----------------
__global__ void k_wcvt(const float* __restrict__ Wf, unsigned short* __restrict__ Wb) {
    int i = blockIdx.x * 256 + threadIdx.x;
    if (i < 128 * 128) Wb[i] = f2bf(Wf[i]);
}

// ---------------- GEMM g = dinv * (x @ W^T) via bf16 MFMA, g stored as bf16 ----------------
__global__ __launch_bounds__(256) void k_gemm(const float* __restrict__ x,
                                              const unsigned short* __restrict__ Wb,
                                              const float* __restrict__ dinv,
                                              unsigned short* __restrict__ gb, int n) {
    int w = threadIdx.x >> 6;
    int l = threadIdx.x & 63;
    int rowbase = blockIdx.x * 128 + w * 32;
    int r16 = l & 15;
    int kg = l >> 4;

    short8 a[2][4];
    float dv[2][4];
    #pragma unroll
    for (int m = 0; m < 2; m++) {
        int row = rowbase + m * 16 + r16;
        int rca = min(row, n - 1);
        const float* base = x + rca * 128;
        #pragma unroll
        for (int q = 0; q < 4; q++) {
            const float4* xp = (const float4*)(base + q * 32 + kg * 8);
            float4 lo = xp[0], hi = xp[1];
            short8 af;
            af[0] = (short)f2bf(lo.x); af[1] = (short)f2bf(lo.y);
            af[2] = (short)f2bf(lo.z); af[3] = (short)f2bf(lo.w);
            af[4] = (short)f2bf(hi.x); af[5] = (short)f2bf(hi.y);
            af[6] = (short)f2bf(hi.z); af[7] = (short)f2bf(hi.w);
            a[m][q] = af;
        }
        #pragma unroll
        for (int r = 0; r < 4; r++)
            dv[m][r] = dinv[min(rowbase + m * 16 + kg * 4 + r, n - 1)];
    }
    for (int t = 0; t < 8; t++) {
        int col = t * 16 + r16;
        short8 b[4];
        #pragma unroll
        for (int q = 0; q < 4; q++)
            b[q] = *(const short8*)(Wb + col * 128 + q * 32 + kg * 8);

        floatx4 acc[2] = {};
        #pragma unroll
        for (int m = 0; m < 2; m++)
            #pragma unroll
            for (int q = 0; q < 4; q++)
                acc[m] = __builtin_amdgcn_mfma_f32_16x16x32_bf16(a[m][q], b[q], acc[m], 0, 0, 0);

        #pragma unroll
        for (int m = 0; m < 2; m++) {
            #pragma unroll
            for (int r = 0; r < 4; r++) {
                int row = rowbase + m * 16 + kg * 4 + r;
                if (row < n) gb[row * 128 + col] = f2bf(acc[m][r] * dv[m][r]);
            }
        }
    }
}

// ---------------- fused2: col-split agg from pre-sorted lists + BN stats ----------------
// 2 blocks per bucket (ch = 64-col half); LDS gets linear copy of sorted src list.
// out_i = dinv_i * (g_i + sum_e g_src); half-wave pairs of edges, 8 loads/lane in flight
__global__ __launch_bounds__(512) void k_fused2(const unsigned int* __restrict__ hp,
        const float* __restrict__ dinv, const int* __restrict__ bcnt,
        const int* __restrict__ offs, const int* __restrict__ deg,
        const unsigned int* __restrict__ b2, float* __restrict__ out,
        float* __restrict__ sums, float* __restrict__ sumsq, int n) {
    __shared__ unsigned int sh_src[CAP];
    __shared__ float dl[128];
    __shared__ int loff[128], ldeg[128];
    __shared__ float ps[8][64], pq[8][64];
    int t = threadIdx.x;
    int w = t >> 6, l = t & 63;
    int bid = blockIdx.x;
    int b = bid >> 1;
    int ch = bid & 1;               // column half
    int half = l >> 5;              // which edge of the pair
    int cu = ch * 32 + (l & 31);    // uint column (2 bf16 cols)
    int nb0 = b * 128;
    int e0 = b * CAP;
    int cnt = bcnt[b];
    int nr = min(128, n - nb0);

    if (t < 128 && t < nr) {
        dl[t] = dinv[nb0 + t];
        loff[t] = offs[nb0 + t];
        ldeg[t] = deg[nb0 + t];
    }
    // linear coalesced copy-in of sorted src list (no conflicts, no atomics)
    for (int i = t; i < cnt; i += 512) sh_src[i] = b2[e0 + i];
    __syncthreads();

    float s0 = 0, s1 = 0, q0 = 0, q1 = 0;
    for (int r = w; r < nr; r += 8) {
        int i = nb0 + r;
        float di = dl[r];
        float ax = 0.f, ay = 0.f;
        int off = loff[r];
        int dg = ldeg[r];
        int e = 0;
        for (; e + 15 < dg; e += 16) {          // 8 loads/lane in flight
            unsigned int hv[8];
            #pragma unroll
            for (int j = 0; j < 8; j++)
                hv[j] = hp[sh_src[off + e + 2 * j + half] * 64 + cu];
            #pragma unroll
            for (int j = 0; j < 8; j++) {
                ax += bflo(hv[j]);
                ay += bfhi(hv[j]);
            }
        }
        for (; e + 3 < dg; e += 4) {            // 2 loads/lane
            unsigned int h0 = hp[sh_src[off + e + half] * 64 + cu];
            unsigned int h1 = hp[sh_src[off + e + 2 + half] * 64 + cu];
            ax += bflo(h0) + bflo(h1);
            ay += bfhi(h0) + bfhi(h1);
        }
        for (; e < dg; e += 2) {
            int idx = e + half;
            if (idx < dg) {
                unsigned int hv = hp[sh_src[off + idx] * 64 + cu];
                ax += bflo(hv);
                ay += bfhi(hv);
            }
        }
        // combine edge-pair halves
        ax += __shfl_xor(ax, 32);
        ay += __shfl_xor(ay, 32);
        if (half == 0) {
            unsigned int sv = hp[i * 64 + cu];  // self term g_i
            float v0 = di * (ax + bflo(sv));
            float v1 = di * (ay + bfhi(sv));
            ((float2*)out)[i * 64 + cu] = make_float2(v0, v1);
            s0 += v0; q0 += v0 * v0;
            s1 += v1; q1 += v1 * v1;
        }
    }

    // BN partial stats: lanes<32 cover cols ch*64 + 2(l&31), +1
    if (half == 0) {
        ps[w][2 * (l & 31)] = s0; ps[w][2 * (l & 31) + 1] = s1;
        pq[w][2 * (l & 31)] = q0; pq[w][2 * (l & 31) + 1] = q1;
    }
    __syncthreads();
    if (t < 64) {
        float s = 0, q = 0;
        #pragma unroll
        for (int j = 0; j < 8; j++) { s += ps[j][t]; q += pq[j][t]; }
        atomicAdd(&sums[ch * 64 + t], s);
        atomicAdd(&sumsq[ch * 64 + t], q);
    }
}

// ---------------- BN normalize + ReLU (in place on f32 out) ----------------
__global__ void k_bn(float* __restrict__ out, const float* __restrict__ sums,
                     const float* __restrict__ sumsq, const float* __restrict__ gamma,
                     const float* __restrict__ beta, int n) {
    int idx = blockIdx.x * 256 + threadIdx.x;
    int total = n * 32;
    if (idx >= total) return;
    int c0 = (idx & 31) * 4;
    float invN = 1.0f / (float)n;
    float4 v = ((const float4*)out)[idx];
    float r[4] = {v.x, v.y, v.z, v.w};
    #pragma unroll
    for (int j = 0; j < 4; j++) {
        int c = c0 + j;
        float mean = sums[c] * invN;
        float var = sumsq[c] * invN - mean * mean;
        float scale = rsqrtf(var + BN_EPS) * gamma[c];
        float o = (r[j] - mean) * scale + beta[c];
        r[j] = fmaxf(o, 0.0f);
    }
    ((float4*)out)[idx] = make_float4(r[0], r[1], r[2], r[3]);
}

extern "C" void kernel_launch(void* const* d_in, const int* in_sizes, int n_in,
                              void* d_out, int out_size, void* d_ws, size_t ws_size,
                              hipStream_t stream) {
    const float* x     = (const float*)d_in[0];
    const int*   ei    = (const int*)d_in[1];     // [2][E]
    const float* W     = (const float*)d_in[2];
    // d_in[3] = b : cancels exactly under training-mode BatchNorm -> unused
    const float* gamma = (const float*)d_in[4];
    const float* beta  = (const float*)d_in[5];
    float* out = (float*)d_out;

    const int n = N_NODES, E = N_EDGES;

    // workspace layout (~43 MB)
    unsigned short* gbuf = (unsigned short*)d_ws;          // 12.8M bf16 (25.6 MB)
    float* dinv   = (float*)(gbuf + 12800000);             // 100k f32
    int*   offs   = (int*)(dinv + 100000);                 // 100k (local, within bucket)
    int*   deg    = offs + 100000;                         // 100k
    float* sums   = (float*)(deg + 100000);                // 128  (zero region start)
    float* sumsq  = sums + 128;                            // 128
    int*   bcnt   = (int*)(sumsq + 128);                   // NBB
    int*   scnt   = bcnt + NBB;                            // SB   (zero region end)
    unsigned short* Wb = (unsigned short*)(scnt + SB);     // 16384 bf16
    unsigned int* b1 = (unsigned int*)(Wb + 16384);        // SB*SCAP u32 (7.0 MB)
    unsigned int* b2 = b1 + SB * SCAP;                     // NBB*CAP u32 (8.6 MB), becomes src-lists

    hipMemsetAsync(sums, 0, (256 + NBB + SB) * sizeof(int), stream);

    k_binA<<<(E + 4095) / 4096, 512, 0, stream>>>(ei, scnt, b1, E);
    k_binB<<<SB * 17, 512, 0, stream>>>(b1, scnt, bcnt, b2);
    k_sortd<<<NBB, 256, 0, stream>>>(b2, bcnt, offs, deg, dinv, n);

    k_wcvt<<<64, 256, 0, stream>>>(W, Wb);
    k_gemm<<<(n + 127) / 128, 256, 0, stream>>>(x, Wb, dinv, gbuf, n);

    k_fused2<<<NBB * 2, 512, 0, stream>>>((const unsigned int*)gbuf, dinv, bcnt, offs, deg,
                                          (const unsigned int*)b2, out, sums, sumsq, n);

    k_bn<<<(n * 32 + 255) / 256, 256, 0, stream>>>(out, sums, sumsq, gamma, beta, n);
}

// Round 13
// 160.856 us; speedup vs baseline: 1.3332x; 1.0421x over previous
//
#include <hip/hip_runtime.h>

#define N_NODES 100000
#define N_EDGES 1600000
#define BN_EPS 1e-5f
#define SB 25          // super-buckets of 4096 nodes
#define SCAP 69632     // super capacity (mean 64000 + 22 sigma), 17*4096
#define NBB 800        // SB*32 buckets of 128 nodes
#define CAP 2688       // bucket capacity (mean 2048 + 14 sigma)

typedef short short8 __attribute__((ext_vector_type(8)));
typedef float floatx4 __attribute__((ext_vector_type(4)));

__device__ __forceinline__ unsigned short f2bf(float f) {
    unsigned int u = __float_as_uint(f);
    unsigned int r = (u + 0x7fffu + ((u >> 16) & 1u)) >> 16;  // RNE
    return (unsigned short)r;
}
__device__ __forceinline__ float bflo(unsigned int v) { return __uint_as_float(v << 16); }
__device__ __forceinline__ float bfhi(unsigned int v) { return __uint_as_float(v & 0xffff0000u); }

// ---------------- pass A: edges -> 25 super-buckets (coalesced runs ~164) ----------------
// code = src | (dst_local12 << 17)
__global__ __launch_bounds__(512) void k_binA(const int* __restrict__ ei,
                                              int* __restrict__ scnt,
                                              unsigned int* __restrict__ b1, int E) {
    __shared__ int hist[32], base[32], gbase[32];
    __shared__ unsigned int stage[4096];
    __shared__ unsigned char stb[4096];
    int tid = threadIdx.x;
    int e0 = blockIdx.x * 4096;
    int cn = min(4096, E - e0);
    if (tid < 32) hist[tid] = 0;
    __syncthreads();

    unsigned int mycode[8];
    short myslot[8];
    signed char myb[8];
    #pragma unroll
    for (int j = 0; j < 8; j++) {
        int idx = j * 512 + tid;
        if (idx < cn) {
            int src = ei[e0 + idx];
            int dst = ei[E + e0 + idx];
            int s = dst >> 12;
            mycode[j] = (unsigned int)src | ((unsigned int)(dst & 4095) << 17);
            myb[j] = (signed char)s;
            myslot[j] = (short)atomicAdd(&hist[s], 1);
        } else myb[j] = -1;
    }
    __syncthreads();
    if (tid == 0) {
        int run = 0;
        for (int s = 0; s < SB; s++) { base[s] = run; run += hist[s]; }
    }
    __syncthreads();
    #pragma unroll
    for (int j = 0; j < 8; j++) {
        if (myb[j] >= 0) {
            int p = base[myb[j]] + myslot[j];
            stage[p] = mycode[j];
            stb[p] = (unsigned char)myb[j];
        }
    }
    if (tid < SB && hist[tid]) gbase[tid] = tid * SCAP + atomicAdd(&scnt[tid], hist[tid]);
    __syncthreads();
    for (int i = tid; i < cn; i += 512) {
        int s = stb[i];
        b1[gbase[s] + (i - base[s])] = stage[i];
    }
}

// ---------------- pass B: super-bucket -> 32 buckets of 128 nodes (runs = 128) ----------------
// final code = src | (dst_local7 << 17)
__global__ __launch_bounds__(512) void k_binB(const unsigned int* __restrict__ b1,
                                              const int* __restrict__ scnt,
                                              int* __restrict__ bcnt,
                                              unsigned int* __restrict__ b2) {
    __shared__ int hist[32], base[32], gbase[32];
    __shared__ unsigned int stage[4096];
    __shared__ unsigned char stb[4096];
    int tid = threadIdx.x;
    int s = blockIdx.x / 17;
    int c = blockIdx.x % 17;
    int cnt = scnt[s];
    int e0 = s * SCAP + c * 4096;
    int cn = min(4096, cnt - c * 4096);
    if (tid < 32) hist[tid] = 0;
    __syncthreads();

    unsigned int mycode[8];
    short myslot[8];
    signed char myb[8];
    #pragma unroll
    for (int j = 0; j < 8; j++) {
        int idx = j * 512 + tid;
        if (idx < cn) {
            unsigned int code = b1[e0 + idx];
            int sub = (code >> 24) & 31;          // dst_local12 >> 7
            mycode[j] = code & 0x00FFFFFFu;       // src | dst_local7<<17
            myb[j] = (signed char)sub;
            myslot[j] = (short)atomicAdd(&hist[sub], 1);
        } else myb[j] = -1;
    }
    __syncthreads();
    if (tid == 0) {
        int run = 0;
        for (int k = 0; k < 32; k++) { base[k] = run; run += hist[k]; }
    }
    __syncthreads();
    #pragma unroll
    for (int j = 0; j < 8; j++) {
        if (myb[j] >= 0) {
            int p = base[myb[j]] + myslot[j];
            stage[p] = mycode[j];
            stb[p] = (unsigned char)myb[j];
        }
    }
    if (tid < 32 && hist[tid]) {
        int gb = s * 32 + tid;
        gbase[tid] = gb * CAP + atomicAdd(&bcnt[gb], hist[tid]);
    }
    __syncthreads();
    for (int i = tid; i < cn; i += 512) {
        int sub = stb[i];
        b2[gbase[sub] + (i - base[sub])] = stage[i];
    }
}

// ---------------- per-bucket: sort codes in place (b2 -> node-grouped src), deg/offs/dinv ----------------
__global__ __launch_bounds__(256) void k_sortd(unsigned int* __restrict__ b2,
        const int* __restrict__ bcnt, int* __restrict__ offs, int* __restrict__ deg,
        float* __restrict__ dinv, int n) {
    __shared__ unsigned int stage[CAP];
    __shared__ int hist[128], hsc[128];
    int b = blockIdx.x, t = threadIdx.x;
    int nb0 = b * 128;
    int e0 = b * CAP;
    int cnt = bcnt[b];
    if (t < 128) hist[t] = 0;
    __syncthreads();
    for (int i = t; i < cnt; i += 256) {
        unsigned int code = b2[e0 + i];
        stage[i] = code;
        atomicAdd(&hist[code >> 17], 1);
    }
    __syncthreads();
    int v = (t < 128) ? hist[t] : 0;
    if (t < 128) hsc[t] = v;
    __syncthreads();
    for (int o = 1; o < 128; o <<= 1) {
        int x = (t < 128 && t >= o) ? hsc[t - o] : 0;
        __syncthreads();
        if (t < 128) hsc[t] += x;
        __syncthreads();
    }
    int nr = min(128, n - nb0);
    if (t < nr) {
        int start = hsc[t] - v;
        offs[nb0 + t] = start;            // local offset within bucket
        deg[nb0 + t] = v;
        dinv[nb0 + t] = rsqrtf((float)(v + 1));
        hist[t] = start;                  // reuse as scatter cursor
    }
    __syncthreads();
    for (int i = t; i < cnt; i += 256) {
        unsigned int code = stage[i];
        int pos = atomicAdd(&hist[code >> 17], 1);
        b2[e0 + pos] = code & 0x1FFFF;    // src only
    }
}

// ---------------- W f32 -> bf16 ----------------
__global__ void k_wcvt(const float* __restrict__ Wf, unsigned short* __restrict__ Wb) {
    int i = blockIdx.x * 256 + threadIdx.x;
    if (i < 128 * 128) Wb[i] = f2bf(Wf[i]);
}

// ---------------- GEMM g = dinv * (x @ W^T) via bf16 MFMA, g stored as bf16 ----------------
__global__ __launch_bounds__(256) void k_gemm(const float* __restrict__ x,
                                              const unsigned short* __restrict__ Wb,
                                              const float* __restrict__ dinv,
                                              unsigned short* __restrict__ gb, int n) {
    int w = threadIdx.x >> 6;
    int l = threadIdx.x & 63;
    int rowbase = blockIdx.x * 128 + w * 32;
    int r16 = l & 15;
    int kg = l >> 4;

    short8 a[2][4];
    float dv[2][4];
    #pragma unroll
    for (int m = 0; m < 2; m++) {
        int row = rowbase + m * 16 + r16;
        int rca = min(row, n - 1);
        const float* base = x + rca * 128;
        #pragma unroll
        for (int q = 0; q < 4; q++) {
            const float4* xp = (const float4*)(base + q * 32 + kg * 8);
            float4 lo = xp[0], hi = xp[1];
            short8 af;
            af[0] = (short)f2bf(lo.x); af[1] = (short)f2bf(lo.y);
            af[2] = (short)f2bf(lo.z); af[3] = (short)f2bf(lo.w);
            af[4] = (short)f2bf(hi.x); af[5] = (short)f2bf(hi.y);
            af[6] = (short)f2bf(hi.z); af[7] = (short)f2bf(hi.w);
            a[m][q] = af;
        }
        #pragma unroll
        for (int r = 0; r < 4; r++)
            dv[m][r] = dinv[min(rowbase + m * 16 + kg * 4 + r, n - 1)];
    }
    for (int t = 0; t < 8; t++) {
        int col = t * 16 + r16;
        short8 b[4];
        #pragma unroll
        for (int q = 0; q < 4; q++)
            b[q] = *(const short8*)(Wb + col * 128 + q * 32 + kg * 8);

        floatx4 acc[2] = {};
        #pragma unroll
        for (int m = 0; m < 2; m++)
            #pragma unroll
            for (int q = 0; q < 4; q++)
                acc[m] = __builtin_amdgcn_mfma_f32_16x16x32_bf16(a[m][q], b[q], acc[m], 0, 0, 0);

        #pragma unroll
        for (int m = 0; m < 2; m++) {
            #pragma unroll
            for (int r = 0; r < 4; r++) {
                int row = rowbase + m * 16 + kg * 4 + r;
                if (row < n) gb[row * 128 + col] = f2bf(acc[m][r] * dv[m][r]);
            }
        }
    }
}

__device__ __forceinline__ void load4u2(const uint2* __restrict__ hp2,
        const unsigned int* __restrict__ sh_src, int off, int e, int qt, int cu2,
        uint2 v[4]) {
    #pragma unroll
    for (int j = 0; j < 4; j++)
        v[j] = hp2[(int)sh_src[off + e + 4 * j + qt] * 32 + cu2];
}
__device__ __forceinline__ void acc4u2(const uint2 v[4], float& a0, float& a1,
                                       float& a2, float& a3) {
    #pragma unroll
    for (int j = 0; j < 4; j++) {
        a0 += bflo(v[j].x); a1 += bfhi(v[j].x);
        a2 += bflo(v[j].y); a3 += bfhi(v[j].y);
    }
}

// ---------------- fused2: col-split agg, uint2 quarter-wave, dual-node streams ----------------
// 2 blocks per bucket (ch = 64-col half); quarter-wave (16 lanes x 8B) per edge half-row;
// wave handles node pair (r, r+8) with interleaved 16-edge chunks -> 8 loads (4KB) in flight.
__global__ __launch_bounds__(512, 8) void k_fused2(const uint2* __restrict__ hp2,
        const float* __restrict__ dinv, const int* __restrict__ bcnt,
        const int* __restrict__ offs, const int* __restrict__ deg,
        const unsigned int* __restrict__ b2, float* __restrict__ out,
        float* __restrict__ sums, float* __restrict__ sumsq, int n) {
    __shared__ unsigned int sh_src[CAP];
    __shared__ float dl[128];
    __shared__ int loff[128], ldeg[128];
    __shared__ float ps[8][64], pq[8][64];
    int t = threadIdx.x;
    int w = t >> 6, l = t & 63;
    int bid = blockIdx.x;
    int b = bid >> 1;
    int ch = bid & 1;               // column half
    int qt = l >> 4;                // quarter 0..3 (which edge of the 4-group)
    int m = l & 15;
    int cu2 = ch * 16 + m;          // uint2 column within row (stride 32)
    int nb0 = b * 128;
    int e0 = b * CAP;
    int cnt = bcnt[b];
    int nr = min(128, n - nb0);

    if (t < 128 && t < nr) {
        dl[t] = dinv[nb0 + t];
        loff[t] = offs[nb0 + t];
        ldeg[t] = deg[nb0 + t];
    }
    // linear coalesced copy-in of sorted src list
    for (int i = t; i < cnt; i += 512) sh_src[i] = b2[e0 + i];
    __syncthreads();

    float ss0 = 0, ss1 = 0, ss2 = 0, ss3 = 0;
    float sq0 = 0, sq1 = 0, sq2 = 0, sq3 = 0;
    for (int rr = w; rr < nr; rr += 16) {
        int rA = rr, rB = rr + 8;
        bool hasB = rB < nr;
        float diA = dl[rA];
        int offA = loff[rA], dgA = ldeg[rA];
        float diB = hasB ? dl[rB] : 0.f;
        int offB = hasB ? loff[rB] : 0;
        int dgB = hasB ? ldeg[rB] : 0;
        float aA0 = 0, aA1 = 0, aA2 = 0, aA3 = 0;
        float aB0 = 0, aB1 = 0, aB2 = 0, aB3 = 0;
        int eA = 0, eB = 0;
        // joint main: 8 loads (4KB) in flight
        while (eA + 15 < dgA && eB + 15 < dgB) {
            uint2 va[4], vb[4];
            load4u2(hp2, sh_src, offA, eA, qt, cu2, va);
            load4u2(hp2, sh_src, offB, eB, qt, cu2, vb);
            acc4u2(va, aA0, aA1, aA2, aA3);
            acc4u2(vb, aB0, aB1, aB2, aB3);
            eA += 16; eB += 16;
        }
        while (eA + 15 < dgA) {
            uint2 va[4];
            load4u2(hp2, sh_src, offA, eA, qt, cu2, va);
            acc4u2(va, aA0, aA1, aA2, aA3);
            eA += 16;
        }
        while (eB + 15 < dgB) {
            uint2 vb[4];
            load4u2(hp2, sh_src, offB, eB, qt, cu2, vb);
            acc4u2(vb, aB0, aB1, aB2, aB3);
            eB += 16;
        }
        // predicated remainders (2 loads per step = 8 edges)
        for (; eA < dgA; eA += 8) {
            int i1 = eA + qt, i2 = eA + 4 + qt;
            uint2 v1 = make_uint2(0u, 0u), v2 = make_uint2(0u, 0u);
            if (i1 < dgA) v1 = hp2[(int)sh_src[offA + i1] * 32 + cu2];
            if (i2 < dgA) v2 = hp2[(int)sh_src[offA + i2] * 32 + cu2];
            aA0 += bflo(v1.x) + bflo(v2.x); aA1 += bfhi(v1.x) + bfhi(v2.x);
            aA2 += bflo(v1.y) + bflo(v2.y); aA3 += bfhi(v1.y) + bfhi(v2.y);
        }
        for (; eB < dgB; eB += 8) {
            int i1 = eB + qt, i2 = eB + 4 + qt;
            uint2 v1 = make_uint2(0u, 0u), v2 = make_uint2(0u, 0u);
            if (i1 < dgB) v1 = hp2[(int)sh_src[offB + i1] * 32 + cu2];
            if (i2 < dgB) v2 = hp2[(int)sh_src[offB + i2] * 32 + cu2];
            aB0 += bflo(v1.x) + bflo(v2.x); aB1 += bfhi(v1.x) + bfhi(v2.x);
            aB2 += bflo(v1.y) + bflo(v2.y); aB3 += bfhi(v1.y) + bfhi(v2.y);
        }
        // reduce across quarters
        aA0 += __shfl_xor(aA0, 16); aA0 += __shfl_xor(aA0, 32);
        aA1 += __shfl_xor(aA1, 16); aA1 += __shfl_xor(aA1, 32);
        aA2 += __shfl_xor(aA2, 16); aA2 += __shfl_xor(aA2, 32);
        aA3 += __shfl_xor(aA3, 16); aA3 += __shfl_xor(aA3, 32);
        aB0 += __shfl_xor(aB0, 16); aB0 += __shfl_xor(aB0, 32);
        aB1 += __shfl_xor(aB1, 16); aB1 += __shfl_xor(aB1, 32);
        aB2 += __shfl_xor(aB2, 16); aB2 += __shfl_xor(aB2, 32);
        aB3 += __shfl_xor(aB3, 16); aB3 += __shfl_xor(aB3, 32);
        if (qt == 0) {
            uint2 sv = hp2[(nb0 + rA) * 32 + cu2];   // self term g_i
            float v0 = diA * (aA0 + bflo(sv.x));
            float v1 = diA * (aA1 + bfhi(sv.x));
            float v2 = diA * (aA2 + bflo(sv.y));
            float v3 = diA * (aA3 + bfhi(sv.y));
            ((float4*)out)[(nb0 + rA) * 32 + cu2] = make_float4(v0, v1, v2, v3);
            ss0 += v0; sq0 += v0 * v0;
            ss1 += v1; sq1 += v1 * v1;
            ss2 += v2; sq2 += v2 * v2;
            ss3 += v3; sq3 += v3 * v3;
            if (hasB) {
                uint2 sb = hp2[(nb0 + rB) * 32 + cu2];
                float u0 = diB * (aB0 + bflo(sb.x));
                float u1 = diB * (aB1 + bfhi(sb.x));
                float u2 = diB * (aB2 + bflo(sb.y));
                float u3 = diB * (aB3 + bfhi(sb.y));
                ((float4*)out)[(nb0 + rB) * 32 + cu2] = make_float4(u0, u1, u2, u3);
                ss0 += u0; sq0 += u0 * u0;
                ss1 += u1; sq1 += u1 * u1;
                ss2 += u2; sq2 += u2 * u2;
                ss3 += u3; sq3 += u3 * u3;
            }
        }
    }

    // BN partial stats: q0 lanes cover cols ch*64 + 4m..4m+3
    if (qt == 0) {
        ps[w][4 * m + 0] = ss0; ps[w][4 * m + 1] = ss1;
        ps[w][4 * m + 2] = ss2; ps[w][4 * m + 3] = ss3;
        pq[w][4 * m + 0] = sq0; pq[w][4 * m + 1] = sq1;
        pq[w][4 * m + 2] = sq2; pq[w][4 * m + 3] = sq3;
    }
    __syncthreads();
    if (t < 64) {
        float s = 0, qq = 0;
        #pragma unroll
        for (int j = 0; j < 8; j++) { s += ps[j][t]; qq += pq[j][t]; }
        atomicAdd(&sums[ch * 64 + t], s);
        atomicAdd(&sumsq[ch * 64 + t], qq);
    }
}

// ---------------- BN normalize + ReLU (in place on f32 out) ----------------
__global__ void k_bn(float* __restrict__ out, const float* __restrict__ sums,
                     const float* __restrict__ sumsq, const float* __restrict__ gamma,
                     const float* __restrict__ beta, int n) {
    int idx = blockIdx.x * 256 + threadIdx.x;
    int total = n * 32;
    if (idx >= total) return;
    int c0 = (idx & 31) * 4;
    float invN = 1.0f / (float)n;
    float4 v = ((const float4*)out)[idx];
    float r[4] = {v.x, v.y, v.z, v.w};
    #pragma unroll
    for (int j = 0; j < 4; j++) {
        int c = c0 + j;
        float mean = sums[c] * invN;
        float var = sumsq[c] * invN - mean * mean;
        float scale = rsqrtf(var + BN_EPS) * gamma[c];
        float o = (r[j] - mean) * scale + beta[c];
        r[j] = fmaxf(o, 0.0f);
    }
    ((float4*)out)[idx] = make_float4(r[0], r[1], r[2], r[3]);
}

extern "C" void kernel_launch(void* const* d_in, const int* in_sizes, int n_in,
                              void* d_out, int out_size, void* d_ws, size_t ws_size,
                              hipStream_t stream) {
    const float* x     = (const float*)d_in[0];
    const int*   ei    = (const int*)d_in[1];     // [2][E]
    const float* W     = (const float*)d_in[2];
    // d_in[3] = b : cancels exactly under training-mode BatchNorm -> unused
    const float* gamma = (const float*)d_in[4];
    const float* beta  = (const float*)d_in[5];
    float* out = (float*)d_out;

    const int n = N_NODES, E = N_EDGES;

    // workspace layout (~43 MB)
    unsigned short* gbuf = (unsigned short*)d_ws;          // 12.8M bf16 (25.6 MB)
    float* dinv   = (float*)(gbuf + 12800000);             // 100k f32
    int*   offs   = (int*)(dinv + 100000);                 // 100k (local, within bucket)
    int*   deg    = offs + 100000;                         // 100k
    float* sums   = (float*)(deg + 100000);                // 128  (zero region start)
    float* sumsq  = sums + 128;                            // 128
    int*   bcnt   = (int*)(sumsq + 128);                   // NBB
    int*   scnt   = bcnt + NBB;                            // SB   (zero region end)
    unsigned short* Wb = (unsigned short*)(scnt + SB);     // 16384 bf16
    unsigned int* b1 = (unsigned int*)(Wb + 16384);        // SB*SCAP u32 (7.0 MB)
    unsigned int* b2 = b1 + SB * SCAP;                     // NBB*CAP u32 (8.6 MB), becomes src-lists

    hipMemsetAsync(sums, 0, (256 + NBB + SB) * sizeof(int), stream);

    k_binA<<<(E + 4095) / 4096, 512, 0, stream>>>(ei, scnt, b1, E);
    k_binB<<<SB * 17, 512, 0, stream>>>(b1, scnt, bcnt, b2);
    k_sortd<<<NBB, 256, 0, stream>>>(b2, bcnt, offs, deg, dinv, n);

    k_wcvt<<<64, 256, 0, stream>>>(W, Wb);
    k_gemm<<<(n + 127) / 128, 256, 0, stream>>>(x, Wb, dinv, gbuf, n);

    k_fused2<<<NBB * 2, 512, 0, stream>>>((const uint2*)gbuf, dinv, bcnt, offs, deg,
                                          (const unsigned int*)b2, out, sums, sumsq, n);

    k_bn<<<(n * 32 + 255) / 256, 256, 0, stream>>>(out, sums, sumsq, gamma, beta, n);
}